// Round 5
// baseline (291.347 us; speedup 1.0000x reference)
//
#include <hip/hip_runtime.h>
#include <hip/hip_bf16.h>
#include <stdint.h>

// Causal self-attention, B=2 T=2048 C=1024 H=16 D=64, scale = 1/sqrt(C) = 1/32.
// cvt(fp32->bf16) -> fused QKV GEMM (dbuf 2-phase prefetch, global_load_lds)
// -> flash attention (dbuf K/V staging, 32 q-rows/wave, swizzled LDS)
// -> out GEMM (dbuf 2-phase prefetch).

typedef __bf16 bf16_t;
typedef __bf16 bf16x8 __attribute__((ext_vector_type(8)));
typedef float f32x4 __attribute__((ext_vector_type(4)));
typedef unsigned short u16x8 __attribute__((ext_vector_type(8)));
typedef unsigned short u16x4 __attribute__((ext_vector_type(4)));

#define MFMA(a, b, c) __builtin_amdgcn_mfma_f32_16x16x32_bf16((a), (b), (c), 0, 0, 0)

// async global->LDS; LDS dest = wave-uniform base, HW adds lane*16
__device__ __forceinline__ void gload_lds16(const void* g, void* l) {
  __builtin_amdgcn_global_load_lds(
      (const __attribute__((address_space(1))) void*)g,
      (__attribute__((address_space(3))) void*)l, 16, 0, 0);
}

// ---------------------------------------------------------------- convert ----
__global__ __launch_bounds__(256) void cvt_f32_to_bf16(const float* __restrict__ in,
                                                       bf16_t* __restrict__ out, int n) {
  int i = (blockIdx.x * 256 + threadIdx.x) * 8;
  if (i + 8 > n) return;
  const float4 a = *reinterpret_cast<const float4*>(in + i);
  const float4 b = *reinterpret_cast<const float4*>(in + i + 4);
  bf16x8 o;
  o[0] = (bf16_t)a.x; o[1] = (bf16_t)a.y; o[2] = (bf16_t)a.z; o[3] = (bf16_t)a.w;
  o[4] = (bf16_t)b.x; o[5] = (bf16_t)b.y; o[6] = (bf16_t)b.z; o[7] = (bf16_t)b.w;
  *reinterpret_cast<bf16x8*>(out + i) = o;
}

__global__ __launch_bounds__(256) void cvt4_f32_to_bf16(
    const float* __restrict__ i0, const float* __restrict__ i1,
    const float* __restrict__ i2, const float* __restrict__ i3,
    bf16_t* __restrict__ o0, bf16_t* __restrict__ o1,
    bf16_t* __restrict__ o2, bf16_t* __restrict__ o3) {
  const float* in; bf16_t* out;
  switch (blockIdx.y) {
    case 0: in = i0; out = o0; break;
    case 1: in = i1; out = o1; break;
    case 2: in = i2; out = o2; break;
    default: in = i3; out = o3; break;
  }
  int i = (blockIdx.x * 256 + threadIdx.x) * 8;
  const float4 a = *reinterpret_cast<const float4*>(in + i);
  const float4 b = *reinterpret_cast<const float4*>(in + i + 4);
  bf16x8 o;
  o[0] = (bf16_t)a.x; o[1] = (bf16_t)a.y; o[2] = (bf16_t)a.z; o[3] = (bf16_t)a.w;
  o[4] = (bf16_t)b.x; o[5] = (bf16_t)b.y; o[6] = (bf16_t)b.z; o[7] = (bf16_t)b.w;
  *reinterpret_cast<bf16x8*>(out + i) = o;
}

// ------------------------------------------------------------- QKV GEMM ------
// C[m][n] = sum_k X[m][k]*W[n][k], M=4096 N=1024 K=1024. 128x128 tile, BK=64,
// 4 waves; DOUBLE-BUFFERED: issue next K-step's global_load_lds before compute.
__global__ __launch_bounds__(256, 2) void qkv_gemm(
    const bf16_t* __restrict__ X, const bf16_t* __restrict__ Wq,
    const bf16_t* __restrict__ Wk, const bf16_t* __restrict__ Wv,
    bf16_t* __restrict__ Q, bf16_t* __restrict__ Ko, bf16_t* __restrict__ Vt) {
  constexpr int Kdim = 1024;
  const int z = blockIdx.z;
  const bf16_t* __restrict__ W = (z == 0) ? Wq : (z == 1) ? Wk : Wv;

  __shared__ __align__(16) bf16_t As[2][128][64];
  __shared__ __align__(16) bf16_t Bs[2][128][64];

  const int tid = threadIdx.x;
  const int lane = tid & 63;
  const int w = tid >> 6;
  const int wr = w >> 1, wc = w & 1;
  const int ln = lane & 15, lh = lane >> 4;
  const int brow = blockIdx.y * 128;
  const int bcol = blockIdx.x * 128;
  const int soff = (w * 4) * 1024 + lane * 16;

  f32x4 acc[4][4] = {};

  auto stage = [&](int bi, int k0) {
#pragma unroll
    for (int s = 0; s < 4; ++s) {
      const int off = soff + s * 1024;
      const int row = off >> 7, colb = off & 127;
      gload_lds16((const char*)X + ((size_t)(brow + row) * Kdim + k0) * 2 + colb,
                  (char*)&As[bi][0][0] + (w * 4 + s) * 1024);
      gload_lds16((const char*)W + ((size_t)(bcol + row) * Kdim + k0) * 2 + colb,
                  (char*)&Bs[bi][0][0] + (w * 4 + s) * 1024);
    }
  };

  stage(0, 0);
  __syncthreads();

  for (int t = 0; t < 16; ++t) {
    const int cur = t & 1;
    if (t < 15) stage(cur ^ 1, (t + 1) * 64);  // prefetch: latency hidden by MFMA below
#pragma unroll
    for (int kk = 0; kk < 2; ++kk) {
      bf16x8 af[4], bfm[4];
#pragma unroll
      for (int i = 0; i < 4; ++i)
        af[i] = *reinterpret_cast<const bf16x8*>(&As[cur][wr * 64 + i * 16 + ln][kk * 32 + lh * 8]);
#pragma unroll
      for (int j = 0; j < 4; ++j)
        bfm[j] = *reinterpret_cast<const bf16x8*>(&Bs[cur][wc * 64 + j * 16 + ln][kk * 32 + lh * 8]);
#pragma unroll
      for (int i = 0; i < 4; ++i)
#pragma unroll
        for (int j = 0; j < 4; ++j)
          acc[i][j] = MFMA(af[i], bfm[j], acc[i][j]);
    }
    __syncthreads();  // drains vmcnt (prefetch writes) + LDS reads of cur
  }

#pragma unroll
  for (int i = 0; i < 4; ++i) {
    const int m0 = brow + wr * 64 + i * 16 + lh * 4;
    const int b = m0 >> 11;
    const int t0 = m0 & 2047;
#pragma unroll
    for (int j = 0; j < 4; ++j) {
      const int n = bcol + wc * 64 + j * 16 + ln;
      const int h = n >> 6, d = n & 63;
      if (z == 2) {
        u16x4 pk;
#pragma unroll
        for (int r = 0; r < 4; ++r)
          pk[r] = __builtin_bit_cast(unsigned short, (bf16_t)acc[i][j][r]);
        *reinterpret_cast<u16x4*>(&Vt[(size_t)((b * 16 + h) * 64 + d) * 2048 + t0]) = pk;
      } else {
        bf16_t* __restrict__ dst = (z == 0) ? Q : Ko;
        const float sc = (z == 0) ? 0.03125f : 1.0f;  // fold 1/sqrt(C)=2^-5 into Q
#pragma unroll
        for (int r = 0; r < 4; ++r)
          dst[(size_t)((b * 16 + h) * 2048 + t0 + r) * 64 + d] = (bf16_t)(acc[i][j][r] * sc);
      }
    }
  }
}

// --------------------------------------------------------- flash attention ---
// grid (x=bh 32, y 16); qblk = y<8 ? y : 23-y  (each CU's 2 blocks sum to 34 tiles).
// Block = 4 waves x 32 q-rows = 128 q-rows. K/V (64-key tiles) DOUBLE-BUFFERED
// in LDS via global_load_lds (pre-swizzled source, T2 swizzled reads); prefetch
// issued before compute so the barrier drain finds loads complete.
#define SWZK(r, c) ((c) ^ (((r) & 7) << 3))        // element-space, 128B rows
#define SWZP(r, c) ((c) ^ ((((r) >> 2) & 3) << 4)) // element-space, P buffer
__global__ __launch_bounds__(256, 2) void attn_fwd(
    const bf16_t* __restrict__ q,    // [BH][T][64], pre-scaled by 1/32
    const bf16_t* __restrict__ kmat, // [BH][T][64]
    const bf16_t* __restrict__ vt,   // [BH][64][T]
    bf16_t* __restrict__ o)          // [B*T][1024]
{
  const int bh = blockIdx.x;
  const int h = bh & 15, b = bh >> 4;
  const int y = blockIdx.y;
  const int qblk = (y < 8) ? y : 23 - y;
  const int tid = threadIdx.x, w = tid >> 6, lane = tid & 63;
  const int ln = lane & 15, lh = lane >> 4;

  __shared__ __align__(16) bf16_t KV[2][2][64][64];  // [buf][K/V][row][col] swizzled
  __shared__ __align__(16) bf16_t Ps[4][32][64];     // per-wave [qrow][key] swizzled

  const size_t base = (size_t)bh * 2048 * 64;
  const bf16_t* __restrict__ kb = kmat + base;
  const bf16_t* __restrict__ vb = vt + base;
  const int q0 = qblk * 128 + w * 32;

  // Q fragments in registers for the whole kernel (2 row-frags x 2 k-halves)
  bf16x8 qf[2][2];
#pragma unroll
  for (int i = 0; i < 2; ++i)
#pragma unroll
    for (int kk = 0; kk < 2; ++kk)
      qf[i][kk] = *reinterpret_cast<const bf16x8*>(
          &q[base + (size_t)(q0 + i * 16 + ln) * 64 + kk * 32 + lh * 8]);

  f32x4 o_acc[2][4] = {};
  float m_s[2][4], l_s[2][4];
#pragma unroll
  for (int i = 0; i < 2; ++i)
#pragma unroll
    for (int r = 0; r < 4; ++r) { m_s[i][r] = -1e30f; l_s[i][r] = 0.0f; }

  // staging: 16 x 1KB chunks (K: 0-7, V: 8-15), wave w -> chunks w*4..w*4+3
  auto stage = [&](int bi, int k0) {
#pragma unroll
    for (int s = 0; s < 4; ++s) {
      const int c = w * 4 + s;
      const int off = (c & 7) * 1024 + lane * 16;
      const int row = off >> 7;
      const int colb = (off & 127) ^ ((row & 7) << 4);  // pre-swizzled source
      if (c < 8)
        gload_lds16((const char*)kb + ((size_t)(k0 + row) * 64) * 2 + colb,
                    (char*)&KV[bi][0][0][0] + (c & 7) * 1024);
      else
        gload_lds16((const char*)vb + ((size_t)row * 2048 + k0) * 2 + colb,
                    (char*)&KV[bi][1][0][0] + (c & 7) * 1024);
    }
  };

  const int ntiles = 2 * qblk + 2;
  stage(0, 0);
  __syncthreads();

  for (int kt = 0; kt < ntiles; ++kt) {
    const int cur = kt & 1;
    if (kt + 1 < ntiles) stage(cur ^ 1, (kt + 1) * 64);  // prefetch next tile
    const int k0 = kt * 64;

    if (k0 <= q0 + 31) {  // else: fully-masked tile for this wave, skip compute
      // S = Q K^T : 32 x 64 per wave
      f32x4 sfr[2][4] = {};
#pragma unroll
      for (int kk = 0; kk < 2; ++kk) {
        bf16x8 kf[4];
#pragma unroll
        for (int j = 0; j < 4; ++j) {
          const int kr = j * 16 + ln;
          kf[j] = *reinterpret_cast<const bf16x8*>(&KV[cur][0][kr][SWZK(kr, kk * 32 + lh * 8)]);
        }
#pragma unroll
        for (int i = 0; i < 2; ++i)
#pragma unroll
          for (int j = 0; j < 4; ++j)
            sfr[i][j] = MFMA(qf[i][kk], kf[j], sfr[i][j]);
      }

      // online softmax (16-lane shfl_xor reduce); mask only near diagonal
      float alpha[2][4];
      const bool diag = (k0 + 63 > q0);
#pragma unroll
      for (int i = 0; i < 2; ++i) {
#pragma unroll
        for (int r = 0; r < 4; ++r) {
          const int qg = q0 + i * 16 + lh * 4 + r;
          float mx = -1e30f;
          if (diag) {
#pragma unroll
            for (int j = 0; j < 4; ++j) {
              const int key = k0 + j * 16 + ln;
              float sv = (key <= qg) ? sfr[i][j][r] : -1e30f;
              sfr[i][j][r] = sv;
              mx = fmaxf(mx, sv);
            }
          } else {
            mx = fmaxf(fmaxf(sfr[i][0][r], sfr[i][1][r]), fmaxf(sfr[i][2][r], sfr[i][3][r]));
          }
#pragma unroll
          for (int off = 1; off < 16; off <<= 1) mx = fmaxf(mx, __shfl_xor(mx, off));
          const float mnew = fmaxf(m_s[i][r], mx);
          const float a = __expf(m_s[i][r] - mnew);
          m_s[i][r] = mnew;
          float rs = 0.0f;
#pragma unroll
          for (int j = 0; j < 4; ++j) {
            const float p = __expf(sfr[i][j][r] - mnew);
            sfr[i][j][r] = p;
            rs += p;
          }
#pragma unroll
          for (int off = 1; off < 16; off <<= 1) rs += __shfl_xor(rs, off);
          l_s[i][r] = l_s[i][r] * a + rs;
          alpha[i][r] = a;
        }
      }

      // P -> per-wave swizzled LDS (re-layout for PV A-fragments); wave-local
#pragma unroll
      for (int i = 0; i < 2; ++i)
#pragma unroll
        for (int j = 0; j < 4; ++j)
#pragma unroll
          for (int r = 0; r < 4; ++r) {
            const int pr = i * 16 + lh * 4 + r;
            Ps[w][pr][SWZP(pr, j * 16 + ln)] = (bf16_t)sfr[i][j][r];
          }
      asm volatile("s_waitcnt lgkmcnt(0)" ::: "memory");  // wave-internal fence

      // rescale O
#pragma unroll
      for (int i = 0; i < 2; ++i)
#pragma unroll
        for (int j = 0; j < 4; ++j)
#pragma unroll
          for (int r = 0; r < 4; ++r) o_acc[i][j][r] *= alpha[i][r];

      // O += P V
#pragma unroll
      for (int kk = 0; kk < 2; ++kk) {
        bf16x8 pa[2], vf[4];
#pragma unroll
        for (int i = 0; i < 2; ++i) {
          const int pr = i * 16 + ln;
          pa[i] = *reinterpret_cast<const bf16x8*>(&Ps[w][pr][SWZP(pr, kk * 32 + lh * 8)]);
        }
#pragma unroll
        for (int j = 0; j < 4; ++j) {
          const int vr = j * 16 + ln;
          vf[j] = *reinterpret_cast<const bf16x8*>(&KV[cur][1][vr][SWZK(vr, kk * 32 + lh * 8)]);
        }
#pragma unroll
        for (int i = 0; i < 2; ++i)
#pragma unroll
          for (int j = 0; j < 4; ++j)
            o_acc[i][j] = MFMA(pa[i], vf[j], o_acc[i][j]);
      }
    }

    __syncthreads();  // all waves done with buf[cur]; prefetch writes drained
  }

  // normalize + store to [B*T][1024]
#pragma unroll
  for (int i = 0; i < 2; ++i) {
#pragma unroll
    for (int r = 0; r < 4; ++r) {
      const float inv = 1.0f / l_s[i][r];
      const int t = q0 + i * 16 + lh * 4 + r;
#pragma unroll
      for (int j = 0; j < 4; ++j) {
        const int d = j * 16 + ln;
        o[(size_t)(b * 2048 + t) * 1024 + h * 64 + d] = (bf16_t)(o_acc[i][j][r] * inv);
      }
    }
  }
}

// ------------------------------------------------------------- out GEMM ------
__global__ __launch_bounds__(256, 2) void out_gemm(
    const bf16_t* __restrict__ X, const bf16_t* __restrict__ W,
    const float* __restrict__ bias, float* __restrict__ Y) {
  constexpr int Kdim = 1024;
  __shared__ __align__(16) bf16_t As[2][128][64];
  __shared__ __align__(16) bf16_t Bs[2][128][64];

  const int tid = threadIdx.x;
  const int lane = tid & 63;
  const int w = tid >> 6;
  const int wr = w >> 1, wc = w & 1;
  const int ln = lane & 15, lh = lane >> 4;
  const int brow = blockIdx.y * 128;
  const int bcol = blockIdx.x * 128;
  const int soff = (w * 4) * 1024 + lane * 16;

  f32x4 acc[4][4] = {};

  auto stage = [&](int bi, int k0) {
#pragma unroll
    for (int s = 0; s < 4; ++s) {
      const int off = soff + s * 1024;
      const int row = off >> 7, colb = off & 127;
      gload_lds16((const char*)X + ((size_t)(brow + row) * Kdim + k0) * 2 + colb,
                  (char*)&As[bi][0][0] + (w * 4 + s) * 1024);
      gload_lds16((const char*)W + ((size_t)(bcol + row) * Kdim + k0) * 2 + colb,
                  (char*)&Bs[bi][0][0] + (w * 4 + s) * 1024);
    }
  };

  stage(0, 0);
  __syncthreads();

  for (int t = 0; t < 16; ++t) {
    const int cur = t & 1;
    if (t < 15) stage(cur ^ 1, (t + 1) * 64);
#pragma unroll
    for (int kk = 0; kk < 2; ++kk) {
      bf16x8 af[4], bfm[4];
#pragma unroll
      for (int i = 0; i < 4; ++i)
        af[i] = *reinterpret_cast<const bf16x8*>(&As[cur][wr * 64 + i * 16 + ln][kk * 32 + lh * 8]);
#pragma unroll
      for (int j = 0; j < 4; ++j)
        bfm[j] = *reinterpret_cast<const bf16x8*>(&Bs[cur][wc * 64 + j * 16 + ln][kk * 32 + lh * 8]);
#pragma unroll
      for (int i = 0; i < 4; ++i)
#pragma unroll
        for (int j = 0; j < 4; ++j)
          acc[i][j] = MFMA(af[i], bfm[j], acc[i][j]);
    }
    __syncthreads();
  }

#pragma unroll
  for (int i = 0; i < 4; ++i) {
    const int m0 = brow + wr * 64 + i * 16 + lh * 4;
#pragma unroll
    for (int j = 0; j < 4; ++j) {
      const int n = bcol + wc * 64 + j * 16 + ln;
      const float bv = bias[n];
#pragma unroll
      for (int r = 0; r < 4; ++r)
        Y[(size_t)(m0 + r) * 1024 + n] = acc[i][j][r] + bv;
    }
  }
}

// ---------------------------------------------------------------- launch -----
extern "C" void kernel_launch(void* const* d_in, const int* in_sizes, int n_in,
                              void* d_out, int out_size, void* d_ws, size_t ws_size,
                              hipStream_t stream) {
  const float* x  = (const float*)d_in[0];
  const float* Wq = (const float*)d_in[1];
  const float* Wk = (const float*)d_in[2];
  const float* Wv = (const float*)d_in[3];
  const float* Wo = (const float*)d_in[4];
  const float* bo = (const float*)d_in[5];

  char* ws = (char*)d_ws;
  bf16_t* xb  = (bf16_t*)(ws);                        // 8 MB  [4096][1024]
  bf16_t* wqb = (bf16_t*)(ws + (size_t)(8u  << 20));  // 2 MB
  bf16_t* wkb = (bf16_t*)(ws + (size_t)(10u << 20));  // 2 MB
  bf16_t* wvb = (bf16_t*)(ws + (size_t)(12u << 20));  // 2 MB
  bf16_t* wob = (bf16_t*)(ws + (size_t)(14u << 20));  // 2 MB
  bf16_t* qb  = (bf16_t*)(ws + (size_t)(16u << 20));  // 8 MB  [2][16][2048][64]
  bf16_t* kb  = (bf16_t*)(ws + (size_t)(24u << 20));  // 8 MB  [2][16][2048][64]
  bf16_t* vtb = (bf16_t*)(ws + (size_t)(32u << 20));  // 8 MB  [2][16][64][2048]
  bf16_t* ob  = (bf16_t*)(ws + (size_t)(40u << 20));  // 8 MB  [4096][1024]

  cvt_f32_to_bf16<<<2048, 256, 0, stream>>>(x, xb, 4096 * 1024);
  cvt4_f32_to_bf16<<<dim3(512, 4), 256, 0, stream>>>(Wq, Wk, Wv, Wo, wqb, wkb, wvb, wob);

  qkv_gemm<<<dim3(8, 32, 3), 256, 0, stream>>>(xb, wqb, wkb, wvb, qb, kb, vtb);
  attn_fwd<<<dim3(32, 16), 256, 0, stream>>>(qb, kb, vtb, ob);
  out_gemm<<<dim3(8, 32), 256, 0, stream>>>(ob, wob, bo, (float*)d_out);
}

// Round 6
// 226.797 us; speedup vs baseline: 1.2846x; 1.2846x over previous
//
#include <hip/hip_runtime.h>
#include <hip/hip_bf16.h>
#include <stdint.h>

// Causal self-attention, B=2 T=2048 C=1024 H=16 D=64, scale = 1/sqrt(C) = 1/32.
// cvt(fp32->bf16) -> fused QKV GEMM (bf16 MFMA, global_load_lds staging)
// -> flash attention (2-wave blocks, uniform 33-tile duration, 8 blocks/CU)
// -> out GEMM.

typedef __bf16 bf16_t;
typedef __bf16 bf16x8 __attribute__((ext_vector_type(8)));
typedef float f32x4 __attribute__((ext_vector_type(4)));
typedef unsigned short u16x8 __attribute__((ext_vector_type(8)));
typedef unsigned short u16x4 __attribute__((ext_vector_type(4)));

#define MFMA(a, b, c) __builtin_amdgcn_mfma_f32_16x16x32_bf16((a), (b), (c), 0, 0, 0)

// async global->LDS; LDS dest = wave-uniform base, HW adds lane*16
__device__ __forceinline__ void gload_lds16(const void* g, void* l) {
  __builtin_amdgcn_global_load_lds(
      (const __attribute__((address_space(1))) void*)g,
      (__attribute__((address_space(3))) void*)l, 16, 0, 0);
}

// ---------------------------------------------------------------- convert ----
__global__ __launch_bounds__(256) void cvt_f32_to_bf16(const float* __restrict__ in,
                                                       bf16_t* __restrict__ out, int n) {
  int i = (blockIdx.x * 256 + threadIdx.x) * 8;
  if (i + 8 > n) return;
  const float4 a = *reinterpret_cast<const float4*>(in + i);
  const float4 b = *reinterpret_cast<const float4*>(in + i + 4);
  bf16x8 o;
  o[0] = (bf16_t)a.x; o[1] = (bf16_t)a.y; o[2] = (bf16_t)a.z; o[3] = (bf16_t)a.w;
  o[4] = (bf16_t)b.x; o[5] = (bf16_t)b.y; o[6] = (bf16_t)b.z; o[7] = (bf16_t)b.w;
  *reinterpret_cast<bf16x8*>(out + i) = o;
}

__global__ __launch_bounds__(256) void cvt4_f32_to_bf16(
    const float* __restrict__ i0, const float* __restrict__ i1,
    const float* __restrict__ i2, const float* __restrict__ i3,
    bf16_t* __restrict__ o0, bf16_t* __restrict__ o1,
    bf16_t* __restrict__ o2, bf16_t* __restrict__ o3) {
  const float* in; bf16_t* out;
  switch (blockIdx.y) {
    case 0: in = i0; out = o0; break;
    case 1: in = i1; out = o1; break;
    case 2: in = i2; out = o2; break;
    default: in = i3; out = o3; break;
  }
  int i = (blockIdx.x * 256 + threadIdx.x) * 8;
  const float4 a = *reinterpret_cast<const float4*>(in + i);
  const float4 b = *reinterpret_cast<const float4*>(in + i + 4);
  bf16x8 o;
  o[0] = (bf16_t)a.x; o[1] = (bf16_t)a.y; o[2] = (bf16_t)a.z; o[3] = (bf16_t)a.w;
  o[4] = (bf16_t)b.x; o[5] = (bf16_t)b.y; o[6] = (bf16_t)b.z; o[7] = (bf16_t)b.w;
  *reinterpret_cast<bf16x8*>(out + i) = o;
}

// ------------------------------------------------------------- QKV GEMM ------
// C[m][n] = sum_k X[m][k] * W[n][k]   (x @ W.T), M=4096, N=1024, K=1024.
// 128x128 tile, BK=64, 4 waves (2x2); staging via global_load_lds width=16.
// (single-buffer: measured better than dbuf in R5)
__global__ __launch_bounds__(256, 2) void qkv_gemm(
    const bf16_t* __restrict__ X, const bf16_t* __restrict__ Wq,
    const bf16_t* __restrict__ Wk, const bf16_t* __restrict__ Wv,
    bf16_t* __restrict__ Q, bf16_t* __restrict__ Ko, bf16_t* __restrict__ Vt) {
  constexpr int Kdim = 1024;
  const int z = blockIdx.z;
  const bf16_t* __restrict__ W = (z == 0) ? Wq : (z == 1) ? Wk : Wv;

  __shared__ __align__(16) bf16_t As[128][64];
  __shared__ __align__(16) bf16_t Bs[128][64];

  const int tid = threadIdx.x;
  const int lane = tid & 63;
  const int w = tid >> 6;
  const int wr = w >> 1, wc = w & 1;
  const int ln = lane & 15, lh = lane >> 4;
  const int brow = blockIdx.y * 128;
  const int bcol = blockIdx.x * 128;

  const int soff = (w * 4) * 1024 + lane * 16;

  f32x4 acc[4][4] = {};

  for (int k0 = 0; k0 < Kdim; k0 += 64) {
#pragma unroll
    for (int s = 0; s < 4; ++s) {
      const int off = soff + s * 1024;
      const int row = off >> 7, colb = off & 127;
      gload_lds16((const char*)X + ((size_t)(brow + row) * Kdim + k0) * 2 + colb,
                  (char*)&As[0][0] + (w * 4 + s) * 1024);
      gload_lds16((const char*)W + ((size_t)(bcol + row) * Kdim + k0) * 2 + colb,
                  (char*)&Bs[0][0] + (w * 4 + s) * 1024);
    }
    __syncthreads();
#pragma unroll
    for (int kk = 0; kk < 2; ++kk) {
      bf16x8 af[4], bfm[4];
#pragma unroll
      for (int i = 0; i < 4; ++i)
        af[i] = *reinterpret_cast<const bf16x8*>(&As[wr * 64 + i * 16 + ln][kk * 32 + lh * 8]);
#pragma unroll
      for (int j = 0; j < 4; ++j)
        bfm[j] = *reinterpret_cast<const bf16x8*>(&Bs[wc * 64 + j * 16 + ln][kk * 32 + lh * 8]);
#pragma unroll
      for (int i = 0; i < 4; ++i)
#pragma unroll
        for (int j = 0; j < 4; ++j)
          acc[i][j] = MFMA(af[i], bfm[j], acc[i][j]);
    }
    __syncthreads();
  }

#pragma unroll
  for (int i = 0; i < 4; ++i) {
    const int m0 = brow + wr * 64 + i * 16 + lh * 4;
    const int b = m0 >> 11;
    const int t0 = m0 & 2047;
#pragma unroll
    for (int j = 0; j < 4; ++j) {
      const int n = bcol + wc * 64 + j * 16 + ln;
      const int h = n >> 6, d = n & 63;
      if (z == 2) {
        u16x4 pk;
#pragma unroll
        for (int r = 0; r < 4; ++r)
          pk[r] = __builtin_bit_cast(unsigned short, (bf16_t)acc[i][j][r]);
        *reinterpret_cast<u16x4*>(&Vt[(size_t)((b * 16 + h) * 64 + d) * 2048 + t0]) = pk;
      } else {
        bf16_t* __restrict__ dst = (z == 0) ? Q : Ko;
        const float sc = (z == 0) ? 0.03125f : 1.0f;  // fold 1/sqrt(C)=2^-5 into Q
#pragma unroll
        for (int r = 0; r < 4; ++r)
          dst[(size_t)((b * 16 + h) * 2048 + t0 + r) * 64 + d] = (bf16_t)(acc[i][j][r] * sc);
      }
    }
  }
}

// --------------------------------------------------------- flash attention ---
// grid (x=bh 32, y 32); block = 128 threads = 2 waves x 16 q-rows = 32 q-rows.
// Each block runs TWO q-blocks sequentially: qq=y then qq=63-y -> exactly 33
// key-tiles per block (uniform duration, no tail, no dispatch-order reliance).
// LDS 20KB -> 8 blocks/CU = 16 waves/CU sustained. K staged by wave0, V by
// wave1 (global_load_lds, pre-swizzled source); single-buffered.
#define SWZK(r, c) ((c) ^ (((r) & 7) << 3))        // element-space, 128B rows
#define SWZP(r, c) ((c) ^ ((((r) >> 2) & 3) << 4)) // element-space, P buffer
__global__ __launch_bounds__(128, 4) void attn_fwd(
    const bf16_t* __restrict__ q,    // [BH][T][64], pre-scaled by 1/32
    const bf16_t* __restrict__ kmat, // [BH][T][64]
    const bf16_t* __restrict__ vt,   // [BH][64][T]
    bf16_t* __restrict__ o)          // [B*T][1024]
{
  const int bh = blockIdx.x;
  const int h = bh & 15, b = bh >> 4;
  const int y = blockIdx.y;
  const int tid = threadIdx.x, w = tid >> 6, lane = tid & 63;
  const int ln = lane & 15, lh = lane >> 4;

  __shared__ __align__(16) bf16_t Ks[64][64];     // [key][d], swizzled
  __shared__ __align__(16) bf16_t Vts[64][64];    // [d][key], swizzled
  __shared__ __align__(16) bf16_t Ps[2][16][64];  // per-wave [qrow][key], swizzled

  const size_t base = (size_t)bh * 2048 * 64;
  const bf16_t* __restrict__ kb = kmat + base;
  const bf16_t* __restrict__ vb = vt + base;

  for (int seg = 0; seg < 2; ++seg) {
    const int qq = seg ? (63 - y) : y;       // 32-row q-block index, 0..63
    const int q0 = qq * 32 + w * 16;         // this wave's first q-row

    // Q fragments in registers for this segment
    bf16x8 qf[2];
#pragma unroll
    for (int kk = 0; kk < 2; ++kk)
      qf[kk] = *reinterpret_cast<const bf16x8*>(
          &q[base + (size_t)(q0 + ln) * 64 + kk * 32 + lh * 8]);

    f32x4 o_acc[4] = {};
    float m_s[4], l_s[4];
#pragma unroll
    for (int r = 0; r < 4; ++r) { m_s[r] = -1e30f; l_s[r] = 0.0f; }

    const int ntiles = (qq >> 1) + 1;  // 64-key tiles; seg0+seg1 = 33 always
    for (int kt = 0; kt < ntiles; ++kt) {
      const int k0 = kt * 64;
      __syncthreads();  // previous tile's (or segment's) LDS reads done
      // stage: wave0 -> K (8 x 1KB chunks), wave1 -> V
#pragma unroll
      for (int s = 0; s < 8; ++s) {
        const int off = s * 1024 + lane * 16;
        const int row = off >> 7;
        const int colb = (off & 127) ^ ((row & 7) << 4);  // pre-swizzled source
        if (w == 0)
          gload_lds16((const char*)kb + ((size_t)(k0 + row) * 64) * 2 + colb,
                      (char*)&Ks[0][0] + s * 1024);
        else
          gload_lds16((const char*)vb + ((size_t)row * 2048 + k0) * 2 + colb,
                      (char*)&Vts[0][0] + s * 1024);
      }
      __syncthreads();  // staged (barrier drains vmcnt)

      // S = Q K^T : 16 x 64 per wave
      f32x4 sfr[4] = {};
#pragma unroll
      for (int kk = 0; kk < 2; ++kk) {
        bf16x8 kf[4];
#pragma unroll
        for (int j = 0; j < 4; ++j) {
          const int kr = j * 16 + ln;
          kf[j] = *reinterpret_cast<const bf16x8*>(&Ks[kr][SWZK(kr, kk * 32 + lh * 8)]);
        }
#pragma unroll
        for (int j = 0; j < 4; ++j)
          sfr[j] = MFMA(qf[kk], kf[j], sfr[j]);
      }

      // online softmax (16-lane shfl_xor reduce); mask only on diagonal tiles
      const bool diag = (k0 + 63 > q0);
      float alpha[4];
#pragma unroll
      for (int r = 0; r < 4; ++r) {
        const int qg = q0 + lh * 4 + r;
        float mx;
        if (diag) {
          mx = -1e30f;
#pragma unroll
          for (int j = 0; j < 4; ++j) {
            const int key = k0 + j * 16 + ln;
            float sv = (key <= qg) ? sfr[j][r] : -1e30f;
            sfr[j][r] = sv;
            mx = fmaxf(mx, sv);
          }
        } else {
          mx = fmaxf(fmaxf(sfr[0][r], sfr[1][r]), fmaxf(sfr[2][r], sfr[3][r]));
        }
#pragma unroll
        for (int off = 1; off < 16; off <<= 1) mx = fmaxf(mx, __shfl_xor(mx, off));
        const float mnew = fmaxf(m_s[r], mx);
        const float a = __expf(m_s[r] - mnew);
        m_s[r] = mnew;
        float rs = 0.0f;
#pragma unroll
        for (int j = 0; j < 4; ++j) {
          const float p = __expf(sfr[j][r] - mnew);
          sfr[j][r] = p;
          rs += p;
        }
#pragma unroll
        for (int off = 1; off < 16; off <<= 1) rs += __shfl_xor(rs, off);
        l_s[r] = l_s[r] * a + rs;
        alpha[r] = a;
      }

      // P -> per-wave swizzled LDS (re-layout for PV A-fragments); wave-local
#pragma unroll
      for (int j = 0; j < 4; ++j)
#pragma unroll
        for (int r = 0; r < 4; ++r) {
          const int pr = lh * 4 + r;
          Ps[w][pr][SWZP(pr, j * 16 + ln)] = (bf16_t)sfr[j][r];
        }
      asm volatile("s_waitcnt lgkmcnt(0)" ::: "memory");  // wave-internal fence

      // rescale O
#pragma unroll
      for (int j = 0; j < 4; ++j)
#pragma unroll
        for (int r = 0; r < 4; ++r) o_acc[j][r] *= alpha[r];

      // O += P V
#pragma unroll
      for (int kk = 0; kk < 2; ++kk) {
        bf16x8 pa = *reinterpret_cast<const bf16x8*>(&Ps[w][ln][SWZP(ln, kk * 32 + lh * 8)]);
        bf16x8 vf[4];
#pragma unroll
        for (int j = 0; j < 4; ++j) {
          const int vr = j * 16 + ln;
          vf[j] = *reinterpret_cast<const bf16x8*>(&Vts[vr][SWZK(vr, kk * 32 + lh * 8)]);
        }
#pragma unroll
        for (int j = 0; j < 4; ++j)
          o_acc[j] = MFMA(pa, vf[j], o_acc[j]);
      }
    }

    // normalize + store this segment's 16 rows
#pragma unroll
    for (int r = 0; r < 4; ++r) {
      const float inv = 1.0f / l_s[r];
      const int t = q0 + lh * 4 + r;
#pragma unroll
      for (int j = 0; j < 4; ++j) {
        const int d = j * 16 + ln;
        o[(size_t)(b * 2048 + t) * 1024 + h * 64 + d] = (bf16_t)(o_acc[j][r] * inv);
      }
    }
  }
}

// ------------------------------------------------------------- out GEMM ------
__global__ __launch_bounds__(256, 2) void out_gemm(
    const bf16_t* __restrict__ X, const bf16_t* __restrict__ W,
    const float* __restrict__ bias, float* __restrict__ Y) {
  constexpr int Kdim = 1024;
  __shared__ __align__(16) bf16_t As[128][64];
  __shared__ __align__(16) bf16_t Bs[128][64];

  const int tid = threadIdx.x;
  const int lane = tid & 63;
  const int w = tid >> 6;
  const int wr = w >> 1, wc = w & 1;
  const int ln = lane & 15, lh = lane >> 4;
  const int brow = blockIdx.y * 128;
  const int bcol = blockIdx.x * 128;
  const int soff = (w * 4) * 1024 + lane * 16;

  f32x4 acc[4][4] = {};

  for (int k0 = 0; k0 < Kdim; k0 += 64) {
#pragma unroll
    for (int s = 0; s < 4; ++s) {
      const int off = soff + s * 1024;
      const int row = off >> 7, colb = off & 127;
      gload_lds16((const char*)X + ((size_t)(brow + row) * Kdim + k0) * 2 + colb,
                  (char*)&As[0][0] + (w * 4 + s) * 1024);
      gload_lds16((const char*)W + ((size_t)(bcol + row) * Kdim + k0) * 2 + colb,
                  (char*)&Bs[0][0] + (w * 4 + s) * 1024);
    }
    __syncthreads();
#pragma unroll
    for (int kk = 0; kk < 2; ++kk) {
      bf16x8 af[4], bfm[4];
#pragma unroll
      for (int i = 0; i < 4; ++i)
        af[i] = *reinterpret_cast<const bf16x8*>(&As[wr * 64 + i * 16 + ln][kk * 32 + lh * 8]);
#pragma unroll
      for (int j = 0; j < 4; ++j)
        bfm[j] = *reinterpret_cast<const bf16x8*>(&Bs[wc * 64 + j * 16 + ln][kk * 32 + lh * 8]);
#pragma unroll
      for (int i = 0; i < 4; ++i)
#pragma unroll
        for (int j = 0; j < 4; ++j)
          acc[i][j] = MFMA(af[i], bfm[j], acc[i][j]);
    }
    __syncthreads();
  }

#pragma unroll
  for (int i = 0; i < 4; ++i) {
    const int m0 = brow + wr * 64 + i * 16 + lh * 4;
#pragma unroll
    for (int j = 0; j < 4; ++j) {
      const int n = bcol + wc * 64 + j * 16 + ln;
      const float bv = bias[n];
#pragma unroll
      for (int r = 0; r < 4; ++r)
        Y[(size_t)(m0 + r) * 1024 + n] = acc[i][j][r] + bv;
    }
  }
}

// ---------------------------------------------------------------- launch -----
extern "C" void kernel_launch(void* const* d_in, const int* in_sizes, int n_in,
                              void* d_out, int out_size, void* d_ws, size_t ws_size,
                              hipStream_t stream) {
  const float* x  = (const float*)d_in[0];
  const float* Wq = (const float*)d_in[1];
  const float* Wk = (const float*)d_in[2];
  const float* Wv = (const float*)d_in[3];
  const float* Wo = (const float*)d_in[4];
  const float* bo = (const float*)d_in[5];

  char* ws = (char*)d_ws;
  bf16_t* xb  = (bf16_t*)(ws);                        // 8 MB  [4096][1024]
  bf16_t* wqb = (bf16_t*)(ws + (size_t)(8u  << 20));  // 2 MB
  bf16_t* wkb = (bf16_t*)(ws + (size_t)(10u << 20));  // 2 MB
  bf16_t* wvb = (bf16_t*)(ws + (size_t)(12u << 20));  // 2 MB
  bf16_t* wob = (bf16_t*)(ws + (size_t)(14u << 20));  // 2 MB
  bf16_t* qb  = (bf16_t*)(ws + (size_t)(16u << 20));  // 8 MB  [2][16][2048][64]
  bf16_t* kb  = (bf16_t*)(ws + (size_t)(24u << 20));  // 8 MB  [2][16][2048][64]
  bf16_t* vtb = (bf16_t*)(ws + (size_t)(32u << 20));  // 8 MB  [2][16][64][2048]
  bf16_t* ob  = (bf16_t*)(ws + (size_t)(40u << 20));  // 8 MB  [4096][1024]

  cvt_f32_to_bf16<<<2048, 256, 0, stream>>>(x, xb, 4096 * 1024);
  cvt4_f32_to_bf16<<<dim3(512, 4), 256, 0, stream>>>(Wq, Wk, Wv, Wo, wqb, wkb, wvb, wob);

  qkv_gemm<<<dim3(8, 32, 3), 256, 0, stream>>>(xb, wqb, wkb, wvb, qb, kb, vtb);
  attn_fwd<<<dim3(32, 32), 128, 0, stream>>>(qb, kb, vtb, ob);
  out_gemm<<<dim3(8, 32), 256, 0, stream>>>(ob, wob, bo, (float*)d_out);
}

// Round 8
// 202.877 us; speedup vs baseline: 1.4361x; 1.1179x over previous
//
#include <hip/hip_runtime.h>
#include <hip/hip_bf16.h>
#include <stdint.h>

// Causal self-attention, B=2 T=2048 C=1024 H=16 D=64, scale = 1/sqrt(C) = 1/32.
// cvt(fp32->bf16) -> fused QKV GEMM (bf16 MFMA, global_load_lds staging)
// -> flash attention (swapped QK^T, lane-local softmax, in-register P, 32x32 MFMA)
// -> out GEMM.

typedef __bf16 bf16_t;
typedef __bf16 bf16x8 __attribute__((ext_vector_type(8)));
typedef float f32x4 __attribute__((ext_vector_type(4)));
typedef float f32x16 __attribute__((ext_vector_type(16)));
typedef unsigned short u16x8 __attribute__((ext_vector_type(8)));
typedef unsigned short u16x4 __attribute__((ext_vector_type(4)));
typedef unsigned int u32x4v __attribute__((ext_vector_type(4)));

#define MFMA(a, b, c) __builtin_amdgcn_mfma_f32_16x16x32_bf16((a), (b), (c), 0, 0, 0)
#define MFMA32(a, b, c) __builtin_amdgcn_mfma_f32_32x32x16_bf16((a), (b), (c), 0, 0, 0)

// async global->LDS; LDS dest = wave-uniform base, HW adds lane*16
__device__ __forceinline__ void gload_lds16(const void* g, void* l) {
  __builtin_amdgcn_global_load_lds(
      (const __attribute__((address_space(1))) void*)g,
      (__attribute__((address_space(3))) void*)l, 16, 0, 0);
}

// pack two f32 -> u32 of 2 bf16 (RNE via cast; compiler may fuse to v_cvt_pk)
__device__ __forceinline__ unsigned pk2(float lo, float hi) {
  unsigned a = (unsigned)__builtin_bit_cast(unsigned short, (bf16_t)lo);
  unsigned b = (unsigned)__builtin_bit_cast(unsigned short, (bf16_t)hi);
  return a | (b << 16);
}

// ---------------------------------------------------------------- convert ----
__global__ __launch_bounds__(256) void cvt_f32_to_bf16(const float* __restrict__ in,
                                                       bf16_t* __restrict__ out, int n) {
  int i = (blockIdx.x * 256 + threadIdx.x) * 8;
  if (i + 8 > n) return;
  const float4 a = *reinterpret_cast<const float4*>(in + i);
  const float4 b = *reinterpret_cast<const float4*>(in + i + 4);
  bf16x8 o;
  o[0] = (bf16_t)a.x; o[1] = (bf16_t)a.y; o[2] = (bf16_t)a.z; o[3] = (bf16_t)a.w;
  o[4] = (bf16_t)b.x; o[5] = (bf16_t)b.y; o[6] = (bf16_t)b.z; o[7] = (bf16_t)b.w;
  *reinterpret_cast<bf16x8*>(out + i) = o;
}

__global__ __launch_bounds__(256) void cvt4_f32_to_bf16(
    const float* __restrict__ i0, const float* __restrict__ i1,
    const float* __restrict__ i2, const float* __restrict__ i3,
    bf16_t* __restrict__ o0, bf16_t* __restrict__ o1,
    bf16_t* __restrict__ o2, bf16_t* __restrict__ o3) {
  const float* in; bf16_t* out;
  switch (blockIdx.y) {
    case 0: in = i0; out = o0; break;
    case 1: in = i1; out = o1; break;
    case 2: in = i2; out = o2; break;
    default: in = i3; out = o3; break;
  }
  int i = (blockIdx.x * 256 + threadIdx.x) * 8;
  const float4 a = *reinterpret_cast<const float4*>(in + i);
  const float4 b = *reinterpret_cast<const float4*>(in + i + 4);
  bf16x8 o;
  o[0] = (bf16_t)a.x; o[1] = (bf16_t)a.y; o[2] = (bf16_t)a.z; o[3] = (bf16_t)a.w;
  o[4] = (bf16_t)b.x; o[5] = (bf16_t)b.y; o[6] = (bf16_t)b.z; o[7] = (bf16_t)b.w;
  *reinterpret_cast<bf16x8*>(out + i) = o;
}

// ------------------------------------------------------------- QKV GEMM ------
// (unchanged from R6 — single-buffer global_load_lds staging)
__global__ __launch_bounds__(256, 2) void qkv_gemm(
    const bf16_t* __restrict__ X, const bf16_t* __restrict__ Wq,
    const bf16_t* __restrict__ Wk, const bf16_t* __restrict__ Wv,
    bf16_t* __restrict__ Q, bf16_t* __restrict__ Ko, bf16_t* __restrict__ Vt) {
  constexpr int Kdim = 1024;
  const int z = blockIdx.z;
  const bf16_t* __restrict__ W = (z == 0) ? Wq : (z == 1) ? Wk : Wv;

  __shared__ __align__(16) bf16_t As[128][64];
  __shared__ __align__(16) bf16_t Bs[128][64];

  const int tid = threadIdx.x;
  const int lane = tid & 63;
  const int w = tid >> 6;
  const int wr = w >> 1, wc = w & 1;
  const int ln = lane & 15, lh = lane >> 4;
  const int brow = blockIdx.y * 128;
  const int bcol = blockIdx.x * 128;

  const int soff = (w * 4) * 1024 + lane * 16;

  f32x4 acc[4][4] = {};

  for (int k0 = 0; k0 < Kdim; k0 += 64) {
#pragma unroll
    for (int s = 0; s < 4; ++s) {
      const int off = soff + s * 1024;
      const int row = off >> 7, colb = off & 127;
      gload_lds16((const char*)X + ((size_t)(brow + row) * Kdim + k0) * 2 + colb,
                  (char*)&As[0][0] + (w * 4 + s) * 1024);
      gload_lds16((const char*)W + ((size_t)(bcol + row) * Kdim + k0) * 2 + colb,
                  (char*)&Bs[0][0] + (w * 4 + s) * 1024);
    }
    __syncthreads();
#pragma unroll
    for (int kk = 0; kk < 2; ++kk) {
      bf16x8 af[4], bfm[4];
#pragma unroll
      for (int i = 0; i < 4; ++i)
        af[i] = *reinterpret_cast<const bf16x8*>(&As[wr * 64 + i * 16 + ln][kk * 32 + lh * 8]);
#pragma unroll
      for (int j = 0; j < 4; ++j)
        bfm[j] = *reinterpret_cast<const bf16x8*>(&Bs[wc * 64 + j * 16 + ln][kk * 32 + lh * 8]);
#pragma unroll
      for (int i = 0; i < 4; ++i)
#pragma unroll
        for (int j = 0; j < 4; ++j)
          acc[i][j] = MFMA(af[i], bfm[j], acc[i][j]);
    }
    __syncthreads();
  }

#pragma unroll
  for (int i = 0; i < 4; ++i) {
    const int m0 = brow + wr * 64 + i * 16 + lh * 4;
    const int b = m0 >> 11;
    const int t0 = m0 & 2047;
#pragma unroll
    for (int j = 0; j < 4; ++j) {
      const int n = bcol + wc * 64 + j * 16 + ln;
      const int h = n >> 6, d = n & 63;
      if (z == 2) {
        u16x4 pk;
#pragma unroll
        for (int r = 0; r < 4; ++r)
          pk[r] = __builtin_bit_cast(unsigned short, (bf16_t)acc[i][j][r]);
        *reinterpret_cast<u16x4*>(&Vt[(size_t)((b * 16 + h) * 64 + d) * 2048 + t0]) = pk;
      } else {
        bf16_t* __restrict__ dst = (z == 0) ? Q : Ko;
        const float sc = (z == 0) ? 0.03125f : 1.0f;  // fold 1/sqrt(C)=2^-5 into Q
#pragma unroll
        for (int r = 0; r < 4; ++r)
          dst[(size_t)((b * 16 + h) * 2048 + t0 + r) * 64 + d] = (bf16_t)(acc[i][j][r] * sc);
      }
    }
  }
}

// --------------------------------------------------------- flash attention ---
// Swapped-operand structure (m214/HK): S^T = mfma32(K, Q^T) so each lane owns
// one q-row's scores -> lane-local softmax (fmax/add trees + one shfl_xor(32)).
// P^T packed to bf16 in-register, redistributed across lane halves, fed as
// PV's B-operand: O^T = mfma32(V^T, P^T). No P LDS buffer.
// Block = 2 waves x 32 q-rows (q-tiles 2y,2y+1: both need y+1 key-tiles).
// K/V staged in LDS (XOR-swizzled via pre-swizzled gload source, as R2/R6).
#define SWZK(r, c) ((c) ^ (((r) & 7) << 3))  // element-space, 128B rows
__global__ __launch_bounds__(128, 2) void attn_fwd(
    const bf16_t* __restrict__ q,    // [BH][T][64], pre-scaled by 1/32
    const bf16_t* __restrict__ kmat, // [BH][T][64]
    const bf16_t* __restrict__ vt,   // [BH][64][T]
    bf16_t* __restrict__ o)          // [B*T][1024]
{
  const int bh = blockIdx.x;
  const int h = bh & 15, b = bh >> 4;
  // per-CU duration balancing: quadruples {a,15-a,16+a,31-a} sum to 66 tiles
  const int yraw = blockIdx.y;
  const int ya = yraw & 7, yk = yraw >> 3;
  const int yy = (yk == 0) ? ya : (yk == 1) ? (15 - ya) : (yk == 2) ? (16 + ya) : (31 - ya);
  const int tid = threadIdx.x, w = tid >> 6, lane = tid & 63;
  const int l31 = lane & 31, hi = lane >> 5;

  __shared__ __align__(16) bf16_t Ks[64][64];   // [key][d], swizzled
  __shared__ __align__(16) bf16_t Vts[64][64];  // [d][key], swizzled

  const size_t base = (size_t)bh * 2048 * 64;
  const bf16_t* __restrict__ kb = kmat + base;
  const bf16_t* __restrict__ vb = vt + base;
  const int q0 = yy * 64 + w * 32;
  const int qg = q0 + l31;  // this lane's q-row

  // Q^T fragments (B-operand of 32x32x16): qf[s] holds Q[qg][s*16+8*hi .. +8]
  bf16x8 qf[4];
#pragma unroll
  for (int s = 0; s < 4; ++s)
    qf[s] = *reinterpret_cast<const bf16x8*>(&q[base + (size_t)qg * 64 + s * 16 + 8 * hi]);

  f32x16 o_acc[2] = {};  // O^T[dg]: d = 32*dg + (r&3)+8*(r>>2)+4*hi, col q = l31
  float m_s = -1e30f, l_s = 0.0f;

  const int ntiles = yy + 1;
  for (int kt = 0; kt < ntiles; ++kt) {
    const int k0 = kt * 64;
    __syncthreads();  // previous tile's LDS reads done
    // stage: wave0 -> K, wave1 -> V (8 x 1KB chunks each, pre-swizzled source)
#pragma unroll
    for (int s = 0; s < 8; ++s) {
      const int off = s * 1024 + lane * 16;
      const int row = off >> 7;
      const int colb = (off & 127) ^ ((row & 7) << 4);
      if (w == 0)
        gload_lds16((const char*)kb + ((size_t)(k0 + row) * 64) * 2 + colb,
                    (char*)&Ks[0][0] + s * 1024);
      else
        gload_lds16((const char*)vb + ((size_t)row * 2048 + k0) * 2 + colb,
                    (char*)&Vts[0][0] + s * 1024);
    }
    __syncthreads();  // staged (barrier drains vmcnt)

    // S^T[key][q] = K · Q^T : two 32x32 tiles (key-group g), K is A-operand
    f32x16 sg[2] = {};
#pragma unroll
    for (int g = 0; g < 2; ++g) {
      const int kr = g * 32 + l31;
#pragma unroll
      for (int s = 0; s < 4; ++s) {
        bf16x8 kf = *reinterpret_cast<const bf16x8*>(&Ks[kr][SWZK(kr, s * 16 + 8 * hi)]);
        sg[g] = MFMA32(kf, qf[s], sg[g]);
      }
    }

    // lane-local online softmax; this lane holds 32 of the row's 64 scores,
    // partner lane^32 the rest. key_local = 32g + (r&3)+8*(r>>2)+4*hi.
    float mx = -1e30f;
    if (kt == ntiles - 1) {  // only the last tile crosses the diagonal
#pragma unroll
      for (int g = 0; g < 2; ++g)
#pragma unroll
        for (int r = 0; r < 16; ++r) {
          const int key = k0 + g * 32 + (r & 3) + 8 * (r >> 2) + 4 * hi;
          float sv = (key <= qg) ? sg[g][r] : -1e30f;
          sg[g][r] = sv;
          mx = fmaxf(mx, sv);
        }
    } else {
#pragma unroll
      for (int g = 0; g < 2; ++g)
#pragma unroll
        for (int r = 0; r < 16; ++r) mx = fmaxf(mx, sg[g][r]);
    }
    mx = fmaxf(mx, __shfl_xor(mx, 32));
    const float mnew = fmaxf(m_s, mx);
    const float alpha = __expf(m_s - mnew);
    m_s = mnew;
    float rs = 0.0f;
#pragma unroll
    for (int g = 0; g < 2; ++g)
#pragma unroll
      for (int r = 0; r < 16; ++r) {
        const float pv = __expf(sg[g][r] - mnew);
        sg[g][r] = pv;
        rs += pv;
      }
    rs += __shfl_xor(rs, 32);
    l_s = l_s * alpha + rs;

    // rescale O
#pragma unroll
    for (int dg = 0; dg < 2; ++dg)
#pragma unroll
      for (int e = 0; e < 16; ++e) o_acc[dg][e] *= alpha;

    // P^T B-fragments: pack pairs to bf16, exchange across lane halves.
    // B[key=16*ks+8*hi+e][q=l31]; word j of slice: keys (8hi+2j, 8hi+2j+1).
    bf16x8 pf[4];
#pragma unroll
    for (int g = 0; g < 2; ++g) {
      unsigned wv[8], tv[8];
#pragma unroll
      for (int i = 0; i < 8; ++i) {
        wv[i] = pk2(sg[g][2 * i], sg[g][2 * i + 1]);
        tv[i] = (unsigned)__shfl_xor((int)wv[i], 32);
      }
#pragma unroll
      for (int hh = 0; hh < 2; ++hh) {
        u32x4v bw;
        bw[0] = hi ? tv[4 * hh + 2] : wv[4 * hh + 0];
        bw[1] = hi ? tv[4 * hh + 3] : wv[4 * hh + 1];
        bw[2] = hi ? wv[4 * hh + 2] : tv[4 * hh + 0];
        bw[3] = hi ? wv[4 * hh + 3] : tv[4 * hh + 1];
        pf[g * 2 + hh] = __builtin_bit_cast(bf16x8, bw);
      }
    }

    // O^T += V^T · P^T (V^T is A-operand, straight from Vts)
#pragma unroll
    for (int dg = 0; dg < 2; ++dg) {
      const int vr = dg * 32 + l31;
#pragma unroll
      for (int ks = 0; ks < 4; ++ks) {
        bf16x8 vf = *reinterpret_cast<const bf16x8*>(&Vts[vr][SWZK(vr, ks * 16 + 8 * hi)]);
        o_acc[dg] = MFMA32(vf, pf[ks], o_acc[dg]);
      }
    }
  }

  // store O^T: reg r -> d = 32*dg + 8*(r>>2) + 4*hi + (r&3); 8B packed stores
  const float inv = 1.0f / l_s;
#pragma unroll
  for (int dg = 0; dg < 2; ++dg)
#pragma unroll
    for (int rr = 0; rr < 4; ++rr) {
      u16x4 pkv;
#pragma unroll
      for (int e = 0; e < 4; ++e)
        pkv[e] = __builtin_bit_cast(unsigned short, (bf16_t)(o_acc[dg][rr * 4 + e] * inv));
      const int d = dg * 32 + rr * 8 + 4 * hi;
      *reinterpret_cast<u16x4*>(&o[(size_t)(b * 2048 + qg) * 1024 + h * 64 + d]) = pkv;
    }
}

// ------------------------------------------------------------- out GEMM ------
__global__ __launch_bounds__(256, 2) void out_gemm(
    const bf16_t* __restrict__ X, const bf16_t* __restrict__ W,
    const float* __restrict__ bias, float* __restrict__ Y) {
  constexpr int Kdim = 1024;
  __shared__ __align__(16) bf16_t As[128][64];
  __shared__ __align__(16) bf16_t Bs[128][64];

  const int tid = threadIdx.x;
  const int lane = tid & 63;
  const int w = tid >> 6;
  const int wr = w >> 1, wc = w & 1;
  const int ln = lane & 15, lh = lane >> 4;
  const int brow = blockIdx.y * 128;
  const int bcol = blockIdx.x * 128;
  const int soff = (w * 4) * 1024 + lane * 16;

  f32x4 acc[4][4] = {};

  for (int k0 = 0; k0 < Kdim; k0 += 64) {
#pragma unroll
    for (int s = 0; s < 4; ++s) {
      const int off = soff + s * 1024;
      const int row = off >> 7, colb = off & 127;
      gload_lds16((const char*)X + ((size_t)(brow + row) * Kdim + k0) * 2 + colb,
                  (char*)&As[0][0] + (w * 4 + s) * 1024);
      gload_lds16((const char*)W + ((size_t)(bcol + row) * Kdim + k0) * 2 + colb,
                  (char*)&Bs[0][0] + (w * 4 + s) * 1024);
    }
    __syncthreads();
#pragma unroll
    for (int kk = 0; kk < 2; ++kk) {
      bf16x8 af[4], bfm[4];
#pragma unroll
      for (int i = 0; i < 4; ++i)
        af[i] = *reinterpret_cast<const bf16x8*>(&As[wr * 64 + i * 16 + ln][kk * 32 + lh * 8]);
#pragma unroll
      for (int j = 0; j < 4; ++j)
        bfm[j] = *reinterpret_cast<const bf16x8*>(&Bs[wc * 64 + j * 16 + ln][kk * 32 + lh * 8]);
#pragma unroll
      for (int i = 0; i < 4; ++i)
#pragma unroll
        for (int j = 0; j < 4; ++j)
          acc[i][j] = MFMA(af[i], bfm[j], acc[i][j]);
    }
    __syncthreads();
  }

#pragma unroll
  for (int i = 0; i < 4; ++i) {
    const int m0 = brow + wr * 64 + i * 16 + lh * 4;
#pragma unroll
    for (int j = 0; j < 4; ++j) {
      const int n = bcol + wc * 64 + j * 16 + ln;
      const float bv = bias[n];
#pragma unroll
      for (int r = 0; r < 4; ++r)
        Y[(size_t)(m0 + r) * 1024 + n] = acc[i][j][r] + bv;
    }
  }
}

// ---------------------------------------------------------------- launch -----
extern "C" void kernel_launch(void* const* d_in, const int* in_sizes, int n_in,
                              void* d_out, int out_size, void* d_ws, size_t ws_size,
                              hipStream_t stream) {
  const float* x  = (const float*)d_in[0];
  const float* Wq = (const float*)d_in[1];
  const float* Wk = (const float*)d_in[2];
  const float* Wv = (const float*)d_in[3];
  const float* Wo = (const float*)d_in[4];
  const float* bo = (const float*)d_in[5];

  char* ws = (char*)d_ws;
  bf16_t* xb  = (bf16_t*)(ws);                        // 8 MB  [4096][1024]
  bf16_t* wqb = (bf16_t*)(ws + (size_t)(8u  << 20));  // 2 MB
  bf16_t* wkb = (bf16_t*)(ws + (size_t)(10u << 20));  // 2 MB
  bf16_t* wvb = (bf16_t*)(ws + (size_t)(12u << 20));  // 2 MB
  bf16_t* wob = (bf16_t*)(ws + (size_t)(14u << 20));  // 2 MB
  bf16_t* qb  = (bf16_t*)(ws + (size_t)(16u << 20));  // 8 MB  [2][16][2048][64]
  bf16_t* kb  = (bf16_t*)(ws + (size_t)(24u << 20));  // 8 MB  [2][16][2048][64]
  bf16_t* vtb = (bf16_t*)(ws + (size_t)(32u << 20));  // 8 MB  [2][16][64][2048]
  bf16_t* ob  = (bf16_t*)(ws + (size_t)(40u << 20));  // 8 MB  [4096][1024]

  cvt_f32_to_bf16<<<2048, 256, 0, stream>>>(x, xb, 4096 * 1024);
  cvt4_f32_to_bf16<<<dim3(512, 4), 256, 0, stream>>>(Wq, Wk, Wv, Wo, wqb, wkb, wvb, wob);

  qkv_gemm<<<dim3(8, 32, 3), 256, 0, stream>>>(xb, wqb, wkb, wvb, qb, kb, vtb);
  attn_fwd<<<dim3(32, 32), 128, 0, stream>>>(qb, kb, vtb, ob);
  out_gemm<<<dim3(8, 32), 256, 0, stream>>>(ob, wob, bo, (float*)d_out);
}

// Round 10
// 192.878 us; speedup vs baseline: 1.5105x; 1.0518x over previous
//
#include <hip/hip_runtime.h>
#include <hip/hip_bf16.h>
#include <stdint.h>

// Causal self-attention, B=2 T=2048 C=1024 H=16 D=64, scale = 1/sqrt(C) = 1/32.
// cvt(fp32->bf16) -> fused QKV GEMM -> flash attention (swapped QK^T, lane-local
// softmax, in-register P, 32x32 MFMA, KVBLK=128) -> out GEMM (64x128 tiles).

typedef __bf16 bf16_t;
typedef __bf16 bf16x8 __attribute__((ext_vector_type(8)));
typedef float f32x4 __attribute__((ext_vector_type(4)));
typedef float f32x16 __attribute__((ext_vector_type(16)));
typedef unsigned short u16x8 __attribute__((ext_vector_type(8)));
typedef unsigned short u16x4 __attribute__((ext_vector_type(4)));
typedef unsigned int u32x4v __attribute__((ext_vector_type(4)));

#define MFMA(a, b, c) __builtin_amdgcn_mfma_f32_16x16x32_bf16((a), (b), (c), 0, 0, 0)
#define MFMA32(a, b, c) __builtin_amdgcn_mfma_f32_32x32x16_bf16((a), (b), (c), 0, 0, 0)

// async global->LDS; LDS dest = wave-uniform base, HW adds lane*16
__device__ __forceinline__ void gload_lds16(const void* g, void* l) {
  __builtin_amdgcn_global_load_lds(
      (const __attribute__((address_space(1))) void*)g,
      (__attribute__((address_space(3))) void*)l, 16, 0, 0);
}

// pack two f32 -> u32 of 2 bf16
__device__ __forceinline__ unsigned pk2(float lo, float hi) {
  unsigned a = (unsigned)__builtin_bit_cast(unsigned short, (bf16_t)lo);
  unsigned b = (unsigned)__builtin_bit_cast(unsigned short, (bf16_t)hi);
  return a | (b << 16);
}

// ---------------------------------------------------------------- convert ----
__global__ __launch_bounds__(256) void cvt_f32_to_bf16(const float* __restrict__ in,
                                                       bf16_t* __restrict__ out, int n) {
  int i = (blockIdx.x * 256 + threadIdx.x) * 8;
  if (i + 8 > n) return;
  const float4 a = *reinterpret_cast<const float4*>(in + i);
  const float4 b = *reinterpret_cast<const float4*>(in + i + 4);
  bf16x8 o;
  o[0] = (bf16_t)a.x; o[1] = (bf16_t)a.y; o[2] = (bf16_t)a.z; o[3] = (bf16_t)a.w;
  o[4] = (bf16_t)b.x; o[5] = (bf16_t)b.y; o[6] = (bf16_t)b.z; o[7] = (bf16_t)b.w;
  *reinterpret_cast<bf16x8*>(out + i) = o;
}

__global__ __launch_bounds__(256) void cvt4_f32_to_bf16(
    const float* __restrict__ i0, const float* __restrict__ i1,
    const float* __restrict__ i2, const float* __restrict__ i3,
    bf16_t* __restrict__ o0, bf16_t* __restrict__ o1,
    bf16_t* __restrict__ o2, bf16_t* __restrict__ o3) {
  const float* in; bf16_t* out;
  switch (blockIdx.y) {
    case 0: in = i0; out = o0; break;
    case 1: in = i1; out = o1; break;
    case 2: in = i2; out = o2; break;
    default: in = i3; out = o3; break;
  }
  int i = (blockIdx.x * 256 + threadIdx.x) * 8;
  const float4 a = *reinterpret_cast<const float4*>(in + i);
  const float4 b = *reinterpret_cast<const float4*>(in + i + 4);
  bf16x8 o;
  o[0] = (bf16_t)a.x; o[1] = (bf16_t)a.y; o[2] = (bf16_t)a.z; o[3] = (bf16_t)a.w;
  o[4] = (bf16_t)b.x; o[5] = (bf16_t)b.y; o[6] = (bf16_t)b.z; o[7] = (bf16_t)b.w;
  *reinterpret_cast<bf16x8*>(out + i) = o;
}

// ------------------------------------------------------------- QKV GEMM ------
// (unchanged from R8 — single-buffer global_load_lds staging, 128x128, 3/CU)
__global__ __launch_bounds__(256, 2) void qkv_gemm(
    const bf16_t* __restrict__ X, const bf16_t* __restrict__ Wq,
    const bf16_t* __restrict__ Wk, const bf16_t* __restrict__ Wv,
    bf16_t* __restrict__ Q, bf16_t* __restrict__ Ko, bf16_t* __restrict__ Vt) {
  constexpr int Kdim = 1024;
  const int z = blockIdx.z;
  const bf16_t* __restrict__ W = (z == 0) ? Wq : (z == 1) ? Wk : Wv;

  __shared__ __align__(16) bf16_t As[128][64];
  __shared__ __align__(16) bf16_t Bs[128][64];

  const int tid = threadIdx.x;
  const int lane = tid & 63;
  const int w = tid >> 6;
  const int wr = w >> 1, wc = w & 1;
  const int ln = lane & 15, lh = lane >> 4;
  const int brow = blockIdx.y * 128;
  const int bcol = blockIdx.x * 128;

  const int soff = (w * 4) * 1024 + lane * 16;

  f32x4 acc[4][4] = {};

  for (int k0 = 0; k0 < Kdim; k0 += 64) {
#pragma unroll
    for (int s = 0; s < 4; ++s) {
      const int off = soff + s * 1024;
      const int row = off >> 7, colb = off & 127;
      gload_lds16((const char*)X + ((size_t)(brow + row) * Kdim + k0) * 2 + colb,
                  (char*)&As[0][0] + (w * 4 + s) * 1024);
      gload_lds16((const char*)W + ((size_t)(bcol + row) * Kdim + k0) * 2 + colb,
                  (char*)&Bs[0][0] + (w * 4 + s) * 1024);
    }
    __syncthreads();
#pragma unroll
    for (int kk = 0; kk < 2; ++kk) {
      bf16x8 af[4], bfm[4];
#pragma unroll
      for (int i = 0; i < 4; ++i)
        af[i] = *reinterpret_cast<const bf16x8*>(&As[wr * 64 + i * 16 + ln][kk * 32 + lh * 8]);
#pragma unroll
      for (int j = 0; j < 4; ++j)
        bfm[j] = *reinterpret_cast<const bf16x8*>(&Bs[wc * 64 + j * 16 + ln][kk * 32 + lh * 8]);
#pragma unroll
      for (int i = 0; i < 4; ++i)
#pragma unroll
        for (int j = 0; j < 4; ++j)
          acc[i][j] = MFMA(af[i], bfm[j], acc[i][j]);
    }
    __syncthreads();
  }

#pragma unroll
  for (int i = 0; i < 4; ++i) {
    const int m0 = brow + wr * 64 + i * 16 + lh * 4;
    const int b = m0 >> 11;
    const int t0 = m0 & 2047;
#pragma unroll
    for (int j = 0; j < 4; ++j) {
      const int n = bcol + wc * 64 + j * 16 + ln;
      const int h = n >> 6, d = n & 63;
      if (z == 2) {
        u16x4 pk;
#pragma unroll
        for (int r = 0; r < 4; ++r)
          pk[r] = __builtin_bit_cast(unsigned short, (bf16_t)acc[i][j][r]);
        *reinterpret_cast<u16x4*>(&Vt[(size_t)((b * 16 + h) * 64 + d) * 2048 + t0]) = pk;
      } else {
        bf16_t* __restrict__ dst = (z == 0) ? Q : Ko;
        const float sc = (z == 0) ? 0.03125f : 1.0f;  // fold 1/sqrt(C)=2^-5 into Q
#pragma unroll
        for (int r = 0; r < 4; ++r)
          dst[(size_t)((b * 16 + h) * 2048 + t0 + r) * 64 + d] = (bf16_t)(acc[i][j][r] * sc);
      }
    }
  }
}

// --------------------------------------------------------- flash attention ---
// Swapped-operand (R8) + KVBLK=128: half the barrier drains, 2x compute per
// stage. S^T = mfma32(K, Q^T), lane-local softmax, in-register P^T, O^T =
// mfma32(V^T, P^T). Block = 2 waves x 32 q-rows; K/V staged via global_load_lds
// with pre-swizzled source. K tile [128][64] (swz c^((r&7)<<3)); V^T tile
// [64][128] (swz c^((r&15)<<3), 256B rows).
#define SWZK(r, c) ((c) ^ (((r) & 7) << 3))
#define SWZV(r, c) ((c) ^ (((r) & 15) << 3))
__global__ __launch_bounds__(128, 2) void attn_fwd(
    const bf16_t* __restrict__ q,    // [BH][T][64], pre-scaled by 1/32
    const bf16_t* __restrict__ kmat, // [BH][T][64]
    const bf16_t* __restrict__ vt,   // [BH][64][T]
    bf16_t* __restrict__ o)          // [B*T][1024]
{
  const int bh = blockIdx.x;
  const int h = bh & 15, b = bh >> 4;
  // quadruples {a,15-a,16+a,31-a}: 128-key tile counts sum to 34 uniformly
  const int yraw = blockIdx.y;
  const int ya = yraw & 7, yk = yraw >> 3;
  const int yy = (yk == 0) ? ya : (yk == 1) ? (15 - ya) : (yk == 2) ? (16 + ya) : (31 - ya);
  const int tid = threadIdx.x, w = tid >> 6, lane = tid & 63;
  const int l31 = lane & 31, hi = lane >> 5;

  __shared__ __align__(16) bf16_t Ks[128][64];   // [key][d], swizzled (16 KB)
  __shared__ __align__(16) bf16_t Vts[64][128];  // [d][key], swizzled (16 KB)

  const size_t base = (size_t)bh * 2048 * 64;
  const bf16_t* __restrict__ kb = kmat + base;
  const bf16_t* __restrict__ vb = vt + base;
  const int q0 = yy * 64 + w * 32;
  const int qg = q0 + l31;  // this lane's q-row

  // Q^T fragments (B-operand of 32x32x16): qf[s] holds Q[qg][s*16+8*hi .. +8]
  bf16x8 qf[4];
#pragma unroll
  for (int s = 0; s < 4; ++s)
    qf[s] = *reinterpret_cast<const bf16x8*>(&q[base + (size_t)qg * 64 + s * 16 + 8 * hi]);

  f32x16 o_acc[2] = {};  // O^T[dg]: d = 32*dg + (r&3)+8*(r>>2)+4*hi, col q = l31
  float m_s = -1e30f, l_s = 0.0f;

  const int ntiles = (yy >> 1) + 1;  // 128-key tiles = ceil((yy+1)/2)
  for (int kt = 0; kt < ntiles; ++kt) {
    const int k0 = kt * 128;
    __syncthreads();  // previous tile's LDS reads done
    // stage: wave0 -> K (16 x 1KB chunks), wave1 -> V (16 chunks)
#pragma unroll
    for (int s = 0; s < 16; ++s) {
      const int off = s * 1024 + lane * 16;
      if (w == 0) {
        const int row = off >> 7;                            // 128B rows, 128 keys
        const int colb = (off & 127) ^ ((row & 7) << 4);     // pre-swizzled source
        gload_lds16((const char*)kb + ((size_t)(k0 + row) * 64) * 2 + colb,
                    (char*)&Ks[0][0] + s * 1024);
      } else {
        const int row = off >> 8;                            // 256B rows, 64 d
        const int colb = (off & 255) ^ ((row & 15) << 4);    // pre-swizzled source
        gload_lds16((const char*)vb + ((size_t)row * 2048 + k0) * 2 + colb,
                    (char*)&Vts[0][0] + s * 1024);
      }
    }
    __syncthreads();  // staged (barrier drains vmcnt)

    // S^T[key][q] = K · Q^T : four 32x32 tiles (key-group g)
    f32x16 sg[4] = {};
#pragma unroll
    for (int g = 0; g < 4; ++g) {
      const int kr = g * 32 + l31;
#pragma unroll
      for (int s = 0; s < 4; ++s) {
        bf16x8 kf = *reinterpret_cast<const bf16x8*>(&Ks[kr][SWZK(kr, s * 16 + 8 * hi)]);
        sg[g] = MFMA32(kf, qf[s], sg[g]);
      }
    }

    // lane-local online softmax; key_local = 32g + (r&3)+8*(r>>2)+4*hi.
    float mx = -1e30f;
    if (kt == ntiles - 1) {  // only the last tile crosses the diagonal
#pragma unroll
      for (int g = 0; g < 4; ++g)
#pragma unroll
        for (int r = 0; r < 16; ++r) {
          const int key = k0 + g * 32 + (r & 3) + 8 * (r >> 2) + 4 * hi;
          float sv = (key <= qg) ? sg[g][r] : -1e30f;
          sg[g][r] = sv;
          mx = fmaxf(mx, sv);
        }
    } else {
#pragma unroll
      for (int g = 0; g < 4; ++g)
#pragma unroll
        for (int r = 0; r < 16; ++r) mx = fmaxf(mx, sg[g][r]);
    }
    mx = fmaxf(mx, __shfl_xor(mx, 32));
    const float mnew = fmaxf(m_s, mx);
    const float alpha = __expf(m_s - mnew);
    m_s = mnew;
    float rs = 0.0f;
#pragma unroll
    for (int g = 0; g < 4; ++g)
#pragma unroll
      for (int r = 0; r < 16; ++r) {
        const float pv = __expf(sg[g][r] - mnew);
        sg[g][r] = pv;
        rs += pv;
      }
    rs += __shfl_xor(rs, 32);
    l_s = l_s * alpha + rs;

    // rescale O
#pragma unroll
    for (int dg = 0; dg < 2; ++dg)
#pragma unroll
      for (int e = 0; e < 16; ++e) o_acc[dg][e] *= alpha;

    // P^T B-fragments: pack pairs to bf16, exchange across lane halves.
    bf16x8 pf[8];
#pragma unroll
    for (int g = 0; g < 4; ++g) {
      unsigned wv[8], tv[8];
#pragma unroll
      for (int i = 0; i < 8; ++i) {
        wv[i] = pk2(sg[g][2 * i], sg[g][2 * i + 1]);
        tv[i] = (unsigned)__shfl_xor((int)wv[i], 32);
      }
#pragma unroll
      for (int hh = 0; hh < 2; ++hh) {
        u32x4v bw;
        bw[0] = hi ? tv[4 * hh + 2] : wv[4 * hh + 0];
        bw[1] = hi ? tv[4 * hh + 3] : wv[4 * hh + 1];
        bw[2] = hi ? wv[4 * hh + 2] : tv[4 * hh + 0];
        bw[3] = hi ? wv[4 * hh + 3] : tv[4 * hh + 1];
        pf[g * 2 + hh] = __builtin_bit_cast(bf16x8, bw);
      }
    }

    // O^T += V^T · P^T (V^T is A-operand, 8 k-slices of 16 keys)
#pragma unroll
    for (int dg = 0; dg < 2; ++dg) {
      const int vr = dg * 32 + l31;
#pragma unroll
      for (int ks = 0; ks < 8; ++ks) {
        bf16x8 vf = *reinterpret_cast<const bf16x8*>(&Vts[vr][SWZV(vr, ks * 16 + 8 * hi)]);
        o_acc[dg] = MFMA32(vf, pf[ks], o_acc[dg]);
      }
    }
  }

  // store O^T: reg r -> d = 32*dg + 8*(r>>2) + 4*hi + (r&3); 8B packed stores
  const float inv = 1.0f / l_s;
#pragma unroll
  for (int dg = 0; dg < 2; ++dg)
#pragma unroll
    for (int rr = 0; rr < 4; ++rr) {
      u16x4 pkv;
#pragma unroll
      for (int e = 0; e < 4; ++e)
        pkv[e] = __builtin_bit_cast(unsigned short, (bf16_t)(o_acc[dg][rr * 4 + e] * inv));
      const int d = dg * 32 + rr * 8 + 4 * hi;
      *reinterpret_cast<u16x4*>(&o[(size_t)(b * 2048 + qg) * 1024 + h * 64 + d]) = pkv;
    }
}

// ------------------------------------------------------------- out GEMM ------
// 64x128 tiles -> grid 512 blocks = 2/CU (was 256 = 1/CU, zero latency hiding).
// 4 waves 2x2 over (64 rows, 128 cols); wave = 32x64 = 2x4 frags.
__global__ __launch_bounds__(256, 2) void out_gemm(
    const bf16_t* __restrict__ X, const bf16_t* __restrict__ W,
    const float* __restrict__ bias, float* __restrict__ Y) {
  constexpr int Kdim = 1024;
  __shared__ __align__(16) bf16_t As[64][64];    // 8 KB
  __shared__ __align__(16) bf16_t Bs[128][64];   // 16 KB

  const int tid = threadIdx.x;
  const int lane = tid & 63;
  const int w = tid >> 6;
  const int wr = w >> 1, wc = w & 1;
  const int ln = lane & 15, lh = lane >> 4;
  const int brow = blockIdx.y * 64;
  const int bcol = blockIdx.x * 128;

  f32x4 acc[2][4] = {};

  for (int k0 = 0; k0 < Kdim; k0 += 64) {
    // 24 x 1KB chunks: 0-7 As, 8-23 Bs; wave w stages chunks w*6 .. w*6+5
#pragma unroll
    for (int s = 0; s < 6; ++s) {
      const int c = w * 6 + s;
      if (c < 8) {
        const int off = c * 1024 + lane * 16;
        const int row = off >> 7, colb = off & 127;
        gload_lds16((const char*)X + ((size_t)(brow + row) * Kdim + k0) * 2 + colb,
                    (char*)&As[0][0] + c * 1024);
      } else {
        const int off = (c - 8) * 1024 + lane * 16;
        const int row = off >> 7, colb = off & 127;
        gload_lds16((const char*)W + ((size_t)(bcol + row) * Kdim + k0) * 2 + colb,
                    (char*)&Bs[0][0] + (c - 8) * 1024);
      }
    }
    __syncthreads();
#pragma unroll
    for (int kk = 0; kk < 2; ++kk) {
      bf16x8 af[2], bfm[4];
#pragma unroll
      for (int i = 0; i < 2; ++i)
        af[i] = *reinterpret_cast<const bf16x8*>(&As[wr * 32 + i * 16 + ln][kk * 32 + lh * 8]);
#pragma unroll
      for (int j = 0; j < 4; ++j)
        bfm[j] = *reinterpret_cast<const bf16x8*>(&Bs[wc * 64 + j * 16 + ln][kk * 32 + lh * 8]);
#pragma unroll
      for (int i = 0; i < 2; ++i)
#pragma unroll
        for (int j = 0; j < 4; ++j)
          acc[i][j] = MFMA(af[i], bfm[j], acc[i][j]);
    }
    __syncthreads();
  }

#pragma unroll
  for (int i = 0; i < 2; ++i) {
    const int m0 = brow + wr * 32 + i * 16 + lh * 4;
#pragma unroll
    for (int j = 0; j < 4; ++j) {
      const int n = bcol + wc * 64 + j * 16 + ln;
      const float bv = bias[n];
#pragma unroll
      for (int r = 0; r < 4; ++r)
        Y[(size_t)(m0 + r) * 1024 + n] = acc[i][j][r] + bv;
    }
  }
}

// ---------------------------------------------------------------- launch -----
extern "C" void kernel_launch(void* const* d_in, const int* in_sizes, int n_in,
                              void* d_out, int out_size, void* d_ws, size_t ws_size,
                              hipStream_t stream) {
  const float* x  = (const float*)d_in[0];
  const float* Wq = (const float*)d_in[1];
  const float* Wk = (const float*)d_in[2];
  const float* Wv = (const float*)d_in[3];
  const float* Wo = (const float*)d_in[4];
  const float* bo = (const float*)d_in[5];

  char* ws = (char*)d_ws;
  bf16_t* xb  = (bf16_t*)(ws);                        // 8 MB  [4096][1024]
  bf16_t* wqb = (bf16_t*)(ws + (size_t)(8u  << 20));  // 2 MB
  bf16_t* wkb = (bf16_t*)(ws + (size_t)(10u << 20));  // 2 MB
  bf16_t* wvb = (bf16_t*)(ws + (size_t)(12u << 20));  // 2 MB
  bf16_t* wob = (bf16_t*)(ws + (size_t)(14u << 20));  // 2 MB
  bf16_t* qb  = (bf16_t*)(ws + (size_t)(16u << 20));  // 8 MB  [2][16][2048][64]
  bf16_t* kb  = (bf16_t*)(ws + (size_t)(24u << 20));  // 8 MB  [2][16][2048][64]
  bf16_t* vtb = (bf16_t*)(ws + (size_t)(32u << 20));  // 8 MB  [2][16][64][2048]
  bf16_t* ob  = (bf16_t*)(ws + (size_t)(40u << 20));  // 8 MB  [4096][1024]

  cvt_f32_to_bf16<<<2048, 256, 0, stream>>>(x, xb, 4096 * 1024);
  cvt4_f32_to_bf16<<<dim3(512, 4), 256, 0, stream>>>(Wq, Wk, Wv, Wo, wqb, wkb, wvb, wob);

  qkv_gemm<<<dim3(8, 32, 3), 256, 0, stream>>>(xb, wqb, wkb, wvb, qb, kb, vtb);
  attn_fwd<<<dim3(32, 32), 128, 0, stream>>>(qb, kb, vtb, ob);
  out_gemm<<<dim3(8, 64), 256, 0, stream>>>(ob, wob, bo, (float*)d_out);
}